// Round 7
// baseline (7630.584 us; speedup 1.0000x reference)
//
#include <hip/hip_runtime.h>

#define NNODE 1024
#define NPT   512
#define MPT   128
#define ETOT  16384

// ---------------------------------------------------------------------------
// Workspace layout (floats):
//  f0   @ 0        : 1024*32      = 32768
//  f1   @ 32768    : 1024*96      = 98304
//  hh   @ 131072   : 4*16384*32   = 2097152   [p][e][k]
//  acc0 @ 2228224  : 1024*32      = 32768
//  acc1 @ 2260992  : 1024*96      = 98304
//  deg  @ 2359296  : 1024
// ---------------------------------------------------------------------------

__global__ void zero_kernel(float* __restrict__ p) {
    const int i = blockIdx.x * 256 + threadIdx.x;   // 129*256 = 33024 float4s
    if (i < 33024) ((float4*)p)[i] = make_float4(0.f, 0.f, 0.f, 0.f);
}

// --------------------------- three_nn + interpolation ----------------------
__global__ void interp_kernel(const float* __restrict__ h0, const float* __restrict__ h1,
                              const float* __restrict__ uph0, const float* __restrict__ uph1,
                              const float* __restrict__ xyz, const float* __restrict__ xyzp,
                              float* __restrict__ f0, float* __restrict__ f1) {
    __shared__ float sd2[128];
    __shared__ float sw[3];
    __shared__ int   sidx[3];
    const int n = blockIdx.x;          // node
    const int t = threadIdx.x;         // 0..127
    const int b = n >> 9;              // batch (N=512)
    const float x = xyz[n*3+0], y = xyz[n*3+1], z = xyz[n*3+2];
    const float* pb = &xyzp[(b*MPT + t)*3];
    const float dx = x - pb[0], dy = y - pb[1], dz = z - pb[2];
    sd2[t] = dx*dx + dy*dy + dz*dz;
    __syncthreads();
    if (t == 0) {
        float bd0 = 3.4e38f, bd1 = 3.4e38f, bd2 = 3.4e38f;
        int   i0 = 0, i1 = 0, i2 = 0;
        for (int i = 0; i < 128; ++i) {
            const float d = sd2[i];
            if (d < bd0)      { bd2 = bd1; i2 = i1; bd1 = bd0; i1 = i0; bd0 = d; i0 = i; }
            else if (d < bd1) { bd2 = bd1; i2 = i1; bd1 = d;   i1 = i; }
            else if (d < bd2) { bd2 = d;   i2 = i; }
        }
        const float inv0 = 1.f / (fmaxf(bd0, 1e-10f) + 1e-8f);
        const float inv1 = 1.f / (fmaxf(bd1, 1e-10f) + 1e-8f);
        const float inv2 = 1.f / (fmaxf(bd2, 1e-10f) + 1e-8f);
        const float s = inv0 + inv1 + inv2;
        sw[0] = inv0 / s; sw[1] = inv1 / s; sw[2] = inv2 / s;
        sidx[0] = i0; sidx[1] = i1; sidx[2] = i2;
    }
    __syncthreads();
    const float w0 = sw[0], w1 = sw[1], w2 = sw[2];
    const int g0 = b*MPT + sidx[0], g1 = b*MPT + sidx[1], g2 = b*MPT + sidx[2];
    if (t < 32) {
        const int c = t;
        float v;
        if (c < 16) v = w0*uph0[g0*16+c] + w1*uph0[g1*16+c] + w2*uph0[g2*16+c];
        else        v = h0[n*16 + (c-16)];
        f0[n*32 + c] = v;
    } else {
        const int q = t - 32, c = q / 3, m = q - c*3;
        float v;
        if (c < 16) v = w0*uph1[(g0*16+c)*3+m] + w1*uph1[(g1*16+c)*3+m] + w2*uph1[(g2*16+c)*3+m];
        else        v = h1[(n*16 + (c-16))*3 + m];
        f1[n*96 + c*3 + m] = v;
    }
}

// --------------------------- radial trunk: hh[4][E][32] --------------------
__global__ void trunk_kernel(const float* __restrict__ r,
                             const float* __restrict__ w1, const float* __restrict__ b1,
                             const float* __restrict__ g1, const float* __restrict__ be1,
                             const float* __restrict__ w2, const float* __restrict__ b2,
                             const float* __restrict__ g2, const float* __restrict__ be2,
                             float* __restrict__ hh) {
    const int tid = blockIdx.x * 256 + threadIdx.x;   // 0..65535
    const int p = tid >> 14, e = tid & 16383;
    const float rv = r[e];
    float a[32];
    float mu = 0.f;
    #pragma unroll
    for (int o = 0; o < 32; ++o) { a[o] = w1[p*32+o]*rv + b1[p*32+o]; mu += a[o]; }
    mu *= (1.f/32.f);
    float var = 0.f;
    #pragma unroll
    for (int o = 0; o < 32; ++o) { const float d = a[o]-mu; var += d*d; }
    var *= (1.f/32.f);
    float rs = 1.f / sqrtf(var + 1e-5f);
    float h[32];
    #pragma unroll
    for (int o = 0; o < 32; ++o)
        h[o] = fmaxf((a[o]-mu)*rs*g1[p*32+o] + be1[p*32+o], 0.f);
    float a2[32];
    mu = 0.f;
    #pragma unroll
    for (int o = 0; o < 32; ++o) {
        float acc = b2[p*32+o];
        const float* wr = &w2[(p*32+o)*32];
        #pragma unroll
        for (int i = 0; i < 32; ++i) acc += wr[i]*h[i];
        a2[o] = acc; mu += acc;
    }
    mu *= (1.f/32.f);
    var = 0.f;
    #pragma unroll
    for (int o = 0; o < 32; ++o) { const float d = a2[o]-mu; var += d*d; }
    var *= (1.f/32.f);
    rs = 1.f / sqrtf(var + 1e-5f);
    float outv[32];
    #pragma unroll
    for (int o = 0; o < 32; ++o)
        outv[o] = fmaxf((a2[o]-mu)*rs*g2[p*32+o] + be2[p*32+o], 0.f);
    float4* hv = (float4*)&hh[tid*32];
    #pragma unroll
    for (int j = 0; j < 8; ++j)
        hv[j] = make_float4(outv[j*4+0], outv[j*4+1], outv[j*4+2], outv[j*4+3]);
}

// --------------------------- per-edge messages (lane = edge) ---------------
// All lanes consume the SAME W3 row -> LDS reads are same-address broadcasts
// (conflict-free, low bandwidth). W3 is staged through double-buffered LDS
// with the issue-early/write-late split so HBM/L2 latency hides under FMAs.
// Block = 128 threads = 128 edges, one quantum q:
//   q=0: pair00 -> acc0       q=1: pair01 -> acc1      q=2: pair10 -> acc0
//   q=3..6: pair11 o-slice [8*(q-3), 8*(q-3)+8) -> acc1
__launch_bounds__(128, 2)
__global__ void msg_kernel(const float* __restrict__ hhg,
                           const float* __restrict__ f0g, const float* __restrict__ f1g,
                           const float* __restrict__ w3_00, const float* __restrict__ b3_00,
                           const float* __restrict__ w3_01, const float* __restrict__ b3_01,
                           const float* __restrict__ w3_10, const float* __restrict__ b3_10,
                           const float* __restrict__ w3_11, const float* __restrict__ b3_11,
                           const float* __restrict__ bas00g, const float* __restrict__ bas01g,
                           const float* __restrict__ bas10g, const float* __restrict__ bas11g,
                           const int* __restrict__ esrc, const int* __restrict__ edst,
                           float* __restrict__ acc0, float* __restrict__ acc1,
                           float* __restrict__ deg) {
    __shared__ float4 wq[2][256];     // chunk of W3 rows: [row][8 float4]
    __shared__ float  bbuf[2][32];    // chunk biases
    const int tid = threadIdx.x;
    const int q   = blockIdx.x >> 7;          // 0..6 (block-uniform)
    const int grp = blockIdx.x & 127;
    const int e   = (grp << 7) + tid;
    const int s   = esrc[e];
    const int d   = edst[e];

    // my edge's hh fragment for this quantum's pair
    const int p = (q < 2) ? q : ((q == 2) ? 2 : 3);
    float4 hh4[8];
    {
        const float4* hv = (const float4*)&hhg[((p << 14) + e) << 5];
        #pragma unroll
        for (int j = 0; j < 8; ++j) hh4[j] = hv[j];
    }

    if (q < 3) {
        const float* hw; const float* hb;
        if (q == 0)      { hw = w3_00; hb = b3_00; }
        else if (q == 1) { hw = w3_01; hb = b3_01; }
        else             { hw = w3_10; hb = b3_10; }

        // per-edge u[c] (the factor multiplying R[o][c] for every o)
        float u[32];
        float bm0 = 0.f, bm1 = 0.f, bm2 = 0.f;
        if (q < 2) {
            const float sc = (q == 0) ? bas00g[e] : 1.0f;
            const float4* f0v = (const float4*)&f0g[s << 5];
            #pragma unroll
            for (int j = 0; j < 8; ++j) {
                const float4 v = f0v[j];
                u[j*4+0] = v.x * sc; u[j*4+1] = v.y * sc;
                u[j*4+2] = v.z * sc; u[j*4+3] = v.w * sc;
            }
            if (q == 0) atomicAdd(&deg[d], 1.0f);
            else { bm0 = bas01g[e*3]; bm1 = bas01g[e*3+1]; bm2 = bas01g[e*3+2]; }
        } else {
            const float bn0 = bas10g[e*3], bn1 = bas10g[e*3+1], bn2 = bas10g[e*3+2];
            const float4* f1v = (const float4*)&f1g[s*96];
            #pragma unroll
            for (int gg = 0; gg < 8; ++gg) {
                const float4 v0 = f1v[gg*3+0], v1 = f1v[gg*3+1], v2 = f1v[gg*3+2];
                u[gg*4+0] = bn0*v0.x + bn1*v0.y + bn2*v0.z;
                u[gg*4+1] = bn0*v0.w + bn1*v1.x + bn2*v1.y;
                u[gg*4+2] = bn0*v1.z + bn1*v1.w + bn2*v2.x;
                u[gg*4+3] = bn0*v2.y + bn1*v2.z + bn2*v2.w;
            }
        }

        // prologue: stage chunk 0 (rows 0..31 = o=0)
        {
            const float4* src = (const float4*)&hw[0];
            wq[0][tid]       = src[tid];
            wq[0][tid + 128] = src[tid + 128];
            if (tid < 32) bbuf[0][tid] = hb[tid];
        }
        #pragma unroll 1
        for (int ch = 0; ch < 32; ++ch) {          // chunk ch == output o
            __syncthreads();
            const int cur = ch & 1, nxt = cur ^ 1;
            float4 r0, r1; float rb;
            if (ch < 31) {                          // issue next-chunk loads EARLY
                const float4* src = (const float4*)&hw[(ch + 1) << 10];
                r0 = src[tid];
                r1 = src[tid + 128];
                if (tid < 32) rb = hb[((ch + 1) << 5) + tid];
            }
            float a = 0.f;
            #pragma unroll
            for (int rr = 0; rr < 32; ++rr) {       // row rr == input c
                float a0 = bbuf[cur][rr], a1 = 0.f, a2 = 0.f, a3 = 0.f;
                #pragma unroll
                for (int kq = 0; kq < 8; ++kq) {
                    const float4 w = wq[cur][rr*8 + kq];   // broadcast
                    a0 = fmaf(w.x, hh4[kq].x, a0);
                    a1 = fmaf(w.y, hh4[kq].y, a1);
                    a2 = fmaf(w.z, hh4[kq].z, a2);
                    a3 = fmaf(w.w, hh4[kq].w, a3);
                }
                a = fmaf((a0 + a1) + (a2 + a3), u[rr], a);
            }
            if (ch < 31) {                          // write-late (vmcnt drained here)
                wq[nxt][tid]       = r0;
                wq[nxt][tid + 128] = r1;
                if (tid < 32) bbuf[nxt][tid] = rb;
            }
            if (q == 1) {
                const int base = ((d << 5) + ch) * 3;
                atomicAdd(&acc1[base+0], a * bm0);
                atomicAdd(&acc1[base+1], a * bm1);
                atomicAdd(&acc1[base+2], a * bm2);
            } else {
                atomicAdd(&acc0[(d << 5) + ch], a);
            }
        }
    } else {
        // ---- pair11, o-slice [ob, ob+8) ----
        const int ob = (q - 3) << 3;
        float bas[27];
        #pragma unroll
        for (int i = 0; i < 27; ++i) bas[i] = bas11g[e*27 + i];
        float acc[8][3];
        #pragma unroll
        for (int oo = 0; oo < 8; ++oo) { acc[oo][0] = 0.f; acc[oo][1] = 0.f; acc[oo][2] = 0.f; }

        // prologue: stage chunk c=0 (24 rows = 8 oo x 3 fi => 192 float4s).
        // NOTE: block has 128 threads, so entries 128..191 need a second
        // access (tid+128) -- this was the R6 correctness bug.
        {
            const int seg0 = tid / 24, off0 = tid - seg0*24;                 // 0..127
            wq[0][tid] = ((const float4*)&w3_11[((ob + seg0)*96) << 5])[off0];
            if (tid < 64) {
                const int i1 = tid + 128, seg1 = i1 / 24, off1 = i1 - seg1*24; // 128..191
                wq[0][i1] = ((const float4*)&w3_11[((ob + seg1)*96) << 5])[off1];
            }
            if (tid < 24) bbuf[0][tid] = b3_11[(ob + tid/3)*96 + (tid - (tid/3)*3)];
        }
        float s0 = f1g[s*96 + 0], s1v = f1g[s*96 + 1], s2 = f1g[s*96 + 2];
        #pragma unroll 1
        for (int c = 0; c < 32; ++c) {
            __syncthreads();
            const int cur = c & 1, nxt = cur ^ 1;
            float4 r0, r1; float rb;
            float n0, n1, n2;
            if (c < 31) {                            // issue next-chunk loads EARLY
                const int cn = c + 1;
                {
                    const int seg = tid / 24, off = tid - seg*24;             // 0..127
                    r0 = ((const float4*)&w3_11[(((ob + seg)*96) + cn*3) << 5])[off];
                }
                if (tid < 64) {
                    const int i1 = tid + 128;
                    const int seg = i1 / 24, off = i1 - seg*24;               // 128..191
                    r1 = ((const float4*)&w3_11[(((ob + seg)*96) + cn*3) << 5])[off];
                }
                if (tid < 24) rb = b3_11[(ob + tid/3)*96 + cn*3 + (tid - (tid/3)*3)];
                n0 = f1g[s*96 + cn*3 + 0];
                n1 = f1g[s*96 + cn*3 + 1];
                n2 = f1g[s*96 + cn*3 + 2];
            }
            float t_[3][3];                          // t_[fi][m]
            #pragma unroll
            for (int fi = 0; fi < 3; ++fi)
                #pragma unroll
                for (int m = 0; m < 3; ++m)
                    t_[fi][m] = bas[m*9 + fi]*s0 + bas[m*9 + 3 + fi]*s1v + bas[m*9 + 6 + fi]*s2;
            #pragma unroll
            for (int oo = 0; oo < 8; ++oo) {
                #pragma unroll
                for (int fi = 0; fi < 3; ++fi) {
                    const int rl = oo*3 + fi;
                    float a0 = bbuf[cur][rl], a1 = 0.f, a2 = 0.f, a3 = 0.f;
                    #pragma unroll
                    for (int kq = 0; kq < 8; ++kq) {
                        const float4 w = wq[cur][rl*8 + kq];   // broadcast
                        a0 = fmaf(w.x, hh4[kq].x, a0);
                        a1 = fmaf(w.y, hh4[kq].y, a1);
                        a2 = fmaf(w.z, hh4[kq].z, a2);
                        a3 = fmaf(w.w, hh4[kq].w, a3);
                    }
                    const float R = (a0 + a1) + (a2 + a3);
                    acc[oo][0] = fmaf(R, t_[fi][0], acc[oo][0]);
                    acc[oo][1] = fmaf(R, t_[fi][1], acc[oo][1]);
                    acc[oo][2] = fmaf(R, t_[fi][2], acc[oo][2]);
                }
            }
            if (c < 31) {                            // write-late
                wq[nxt][tid] = r0;
                if (tid < 64)  wq[nxt][tid + 128] = r1;
                if (tid < 24)  bbuf[nxt][tid] = rb;
                s0 = n0; s1v = n1; s2 = n2;
            }
        }
        #pragma unroll
        for (int oo = 0; oo < 8; ++oo) {
            const int base = ((d << 5) + ob + oo) * 3;
            atomicAdd(&acc1[base+0], acc[oo][0]);
            atomicAdd(&acc1[base+1], acc[oo][1]);
            atomicAdd(&acc1[base+2], acc[oo][2]);
        }
    }
}

// --------------------------- node epilogue: mean + self + GNormSE3 ---------
__launch_bounds__(256)
__global__ void epi_kernel(const float* __restrict__ acc0, const float* __restrict__ acc1,
                           const float* __restrict__ deg,
                           const float* __restrict__ f0, const float* __restrict__ f1,
                           const float* __restrict__ sw0, const float* __restrict__ sw1,
                           const float* __restrict__ g0v, const float* __restrict__ b0v,
                           const float* __restrict__ nw0, const float* __restrict__ nb0,
                           const float* __restrict__ g1v, const float* __restrict__ b1v,
                           const float* __restrict__ nw1, const float* __restrict__ nb1,
                           float* __restrict__ out) {
    __shared__ float s_sw0[1024], s_sw1[1024], s_nw0[1024], s_nw1[1024];
    __shared__ float s_act0[8][33], s_act1[8][33];
    const int tid = threadIdx.x;
    #pragma unroll
    for (int j = 0; j < 4; ++j) {
        s_sw0[tid + 256*j] = sw0[tid + 256*j];
        s_sw1[tid + 256*j] = sw1[tid + 256*j];
        s_nw0[tid + 256*j] = nw0[tid + 256*j];
        s_nw1[tid + 256*j] = nw1[tid + 256*j];
    }
    const int o = tid & 31, nl = tid >> 5;
    const int n = blockIdx.x * 8 + nl;
    const float dr = deg[n];
    const float dc = fmaxf(dr, 1.0f);
    float v0 = acc0[n*32 + o] / dc;
    float v1[3];
    #pragma unroll
    for (int m = 0; m < 3; ++m) v1[m] = acc1[(n*32 + o)*3 + m] / dc;
    __syncthreads();
    if (dr > 0.f) {   // self-interaction gate: identical to deg/deg_clamped
        #pragma unroll
        for (int c = 0; c < 32; ++c) {
            v0 += s_sw0[o*32 + c] * f0[n*32 + c];
            const float w1c = s_sw1[o*32 + c];
            #pragma unroll
            for (int m = 0; m < 3; ++m) v1[m] += w1c * f1[(n*32 + c)*3 + m];
        }
    }
    const float nrm0 = fmaxf(fabsf(v0), 1e-12f);
    const float nrm1 = fmaxf(sqrtf(v1[0]*v1[0] + v1[1]*v1[1] + v1[2]*v1[2]), 1e-12f);
    float mu0 = nrm0, mu1 = nrm1;
    #pragma unroll
    for (int msk = 16; msk >= 1; msk >>= 1) { mu0 += __shfl_xor(mu0, msk); mu1 += __shfl_xor(mu1, msk); }
    mu0 *= (1.f/32.f); mu1 *= (1.f/32.f);
    const float d0 = nrm0 - mu0, d1 = nrm1 - mu1;
    float s0 = d0*d0, s1 = d1*d1;
    #pragma unroll
    for (int msk = 16; msk >= 1; msk >>= 1) { s0 += __shfl_xor(s0, msk); s1 += __shfl_xor(s1, msk); }
    const float var0 = s0*(1.f/32.f), var1 = s1*(1.f/32.f);
    const float a0 = fmaxf(d0 / sqrtf(var0 + 1e-5f) * g0v[o] + b0v[o], 0.f);
    const float a1 = fmaxf(d1 / sqrtf(var1 + 1e-5f) * g1v[o] + b1v[o], 0.f);
    s_act0[nl][o] = a0; s_act1[nl][o] = a1;
    __syncthreads();
    float t0 = nb0[o], t1 = nb1[o];
    #pragma unroll
    for (int c = 0; c < 32; ++c) {
        t0 += s_act0[nl][c] * s_nw0[o*32 + c];
        t1 += s_act1[nl][c] * s_nw1[o*32 + c];
    }
    float4 ov;
    ov.x = t0 * (v0 / nrm0);
    ov.y = t1 * (v1[0] / nrm1);
    ov.z = t1 * (v1[1] / nrm1);
    ov.w = t1 * (v1[2] / nrm1);
    *(float4*)&out[(n*32 + o)*4] = ov;
}

// ---------------------------------------------------------------------------
extern "C" void kernel_launch(void* const* d_in, const int* in_sizes, int n_in,
                              void* d_out, int out_size, void* d_ws, size_t ws_size,
                              hipStream_t stream) {
    const float* h0    = (const float*)d_in[0];
    const float* h1    = (const float*)d_in[1];
    const float* uph0  = (const float*)d_in[2];
    const float* uph1  = (const float*)d_in[3];
    const float* xyz   = (const float*)d_in[4];
    const float* xyzp  = (const float*)d_in[5];
    const float* r     = (const float*)d_in[6];
    const float* bas00 = (const float*)d_in[7];
    const float* bas01 = (const float*)d_in[8];
    const float* bas10 = (const float*)d_in[9];
    const float* bas11 = (const float*)d_in[10];
    const float* rw1   = (const float*)d_in[11];
    const float* rb1   = (const float*)d_in[12];
    const float* rg1   = (const float*)d_in[13];
    const float* rbe1  = (const float*)d_in[14];
    const float* rw2   = (const float*)d_in[15];
    const float* rb2   = (const float*)d_in[16];
    const float* rg2   = (const float*)d_in[17];
    const float* rbe2  = (const float*)d_in[18];
    const float* w00   = (const float*)d_in[19];
    const float* b00   = (const float*)d_in[20];
    const float* w01   = (const float*)d_in[21];
    const float* b01   = (const float*)d_in[22];
    const float* w10   = (const float*)d_in[23];
    const float* b10   = (const float*)d_in[24];
    const float* w11   = (const float*)d_in[25];
    const float* b11   = (const float*)d_in[26];
    const float* sw0   = (const float*)d_in[27];
    const float* sw1   = (const float*)d_in[28];
    const float* g0    = (const float*)d_in[29];
    const float* bb0   = (const float*)d_in[30];
    const float* nw0   = (const float*)d_in[31];
    const float* nb0   = (const float*)d_in[32];
    const float* g1    = (const float*)d_in[33];
    const float* bb1   = (const float*)d_in[34];
    const float* nw1   = (const float*)d_in[35];
    const float* nb1   = (const float*)d_in[36];
    const int*   esrc  = (const int*)d_in[37];
    const int*   edst  = (const int*)d_in[38];

    float* ws   = (float*)d_ws;
    float* f0   = ws;
    float* f1   = ws + 32768;
    float* hh   = ws + 131072;
    float* acc0 = ws + 2228224;
    float* acc1 = ws + 2260992;
    float* degb = ws + 2359296;
    float* out  = (float*)d_out;

    zero_kernel<<<129, 256, 0, stream>>>(acc0);                    // zeros acc0|acc1|deg
    interp_kernel<<<1024, 128, 0, stream>>>(h0, h1, uph0, uph1, xyz, xyzp, f0, f1);
    trunk_kernel<<<256, 256, 0, stream>>>(r, rw1, rb1, rg1, rbe1, rw2, rb2, rg2, rbe2, hh);
    msg_kernel<<<896, 128, 0, stream>>>(hh, f0, f1, w00, b00, w01, b01, w10, b10, w11, b11,
                                        bas00, bas01, bas10, bas11, esrc, edst, acc0, acc1, degb);
    epi_kernel<<<128, 256, 0, stream>>>(acc0, acc1, degb, f0, f1, sw0, sw1,
                                        g0, bb0, nw0, nb0, g1, bb1, nw1, nb1, out);
}

// Round 8
// 3641.275 us; speedup vs baseline: 2.0956x; 2.0956x over previous
//
#include <hip/hip_runtime.h>

#define NNODE 1024
#define NPT   512
#define MPT   128
#define ETOT  16384

// ---------------------------------------------------------------------------
// Workspace layout (floats):
//  f0   @ 0        : 1024*32      = 32768
//  f1   @ 32768    : 1024*96      = 98304
//  hh   @ 131072   : 4*16384*32   = 2097152   [p][e][k]
//  acc0 @ 2228224  : 1024*32      = 32768
//  acc1 @ 2260992  : 1024*96      = 98304
//  deg  @ 2359296  : 1024
// ---------------------------------------------------------------------------

__global__ void zero_kernel(float* __restrict__ p) {
    const int i = blockIdx.x * 256 + threadIdx.x;   // 129*256 = 33024 float4s
    if (i < 33024) ((float4*)p)[i] = make_float4(0.f, 0.f, 0.f, 0.f);
}

// --------------------------- three_nn + interpolation ----------------------
__global__ void interp_kernel(const float* __restrict__ h0, const float* __restrict__ h1,
                              const float* __restrict__ uph0, const float* __restrict__ uph1,
                              const float* __restrict__ xyz, const float* __restrict__ xyzp,
                              float* __restrict__ f0, float* __restrict__ f1) {
    __shared__ float sd2[128];
    __shared__ float sw[3];
    __shared__ int   sidx[3];
    const int n = blockIdx.x;          // node
    const int t = threadIdx.x;         // 0..127
    const int b = n >> 9;              // batch (N=512)
    const float x = xyz[n*3+0], y = xyz[n*3+1], z = xyz[n*3+2];
    const float* pb = &xyzp[(b*MPT + t)*3];
    const float dx = x - pb[0], dy = y - pb[1], dz = z - pb[2];
    sd2[t] = dx*dx + dy*dy + dz*dz;
    __syncthreads();
    if (t == 0) {
        float bd0 = 3.4e38f, bd1 = 3.4e38f, bd2 = 3.4e38f;
        int   i0 = 0, i1 = 0, i2 = 0;
        for (int i = 0; i < 128; ++i) {
            const float d = sd2[i];
            if (d < bd0)      { bd2 = bd1; i2 = i1; bd1 = bd0; i1 = i0; bd0 = d; i0 = i; }
            else if (d < bd1) { bd2 = bd1; i2 = i1; bd1 = d;   i1 = i; }
            else if (d < bd2) { bd2 = d;   i2 = i; }
        }
        const float inv0 = 1.f / (fmaxf(bd0, 1e-10f) + 1e-8f);
        const float inv1 = 1.f / (fmaxf(bd1, 1e-10f) + 1e-8f);
        const float inv2 = 1.f / (fmaxf(bd2, 1e-10f) + 1e-8f);
        const float s = inv0 + inv1 + inv2;
        sw[0] = inv0 / s; sw[1] = inv1 / s; sw[2] = inv2 / s;
        sidx[0] = i0; sidx[1] = i1; sidx[2] = i2;
    }
    __syncthreads();
    const float w0 = sw[0], w1 = sw[1], w2 = sw[2];
    const int g0 = b*MPT + sidx[0], g1 = b*MPT + sidx[1], g2 = b*MPT + sidx[2];
    if (t < 32) {
        const int c = t;
        float v;
        if (c < 16) v = w0*uph0[g0*16+c] + w1*uph0[g1*16+c] + w2*uph0[g2*16+c];
        else        v = h0[n*16 + (c-16)];
        f0[n*32 + c] = v;
    } else {
        const int q = t - 32, c = q / 3, m = q - c*3;
        float v;
        if (c < 16) v = w0*uph1[(g0*16+c)*3+m] + w1*uph1[(g1*16+c)*3+m] + w2*uph1[(g2*16+c)*3+m];
        else        v = h1[(n*16 + (c-16))*3 + m];
        f1[n*96 + c*3 + m] = v;
    }
}

// --------------------------- radial trunk: hh[4][E][32] --------------------
__global__ void trunk_kernel(const float* __restrict__ r,
                             const float* __restrict__ w1, const float* __restrict__ b1,
                             const float* __restrict__ g1, const float* __restrict__ be1,
                             const float* __restrict__ w2, const float* __restrict__ b2,
                             const float* __restrict__ g2, const float* __restrict__ be2,
                             float* __restrict__ hh) {
    const int tid = blockIdx.x * 256 + threadIdx.x;   // 0..65535
    const int p = tid >> 14, e = tid & 16383;
    const float rv = r[e];
    float a[32];
    float mu = 0.f;
    #pragma unroll
    for (int o = 0; o < 32; ++o) { a[o] = w1[p*32+o]*rv + b1[p*32+o]; mu += a[o]; }
    mu *= (1.f/32.f);
    float var = 0.f;
    #pragma unroll
    for (int o = 0; o < 32; ++o) { const float d = a[o]-mu; var += d*d; }
    var *= (1.f/32.f);
    float rs = 1.f / sqrtf(var + 1e-5f);
    float h[32];
    #pragma unroll
    for (int o = 0; o < 32; ++o)
        h[o] = fmaxf((a[o]-mu)*rs*g1[p*32+o] + be1[p*32+o], 0.f);
    float a2[32];
    mu = 0.f;
    #pragma unroll
    for (int o = 0; o < 32; ++o) {
        float acc = b2[p*32+o];
        const float* wr = &w2[(p*32+o)*32];
        #pragma unroll
        for (int i = 0; i < 32; ++i) acc += wr[i]*h[i];
        a2[o] = acc; mu += acc;
    }
    mu *= (1.f/32.f);
    var = 0.f;
    #pragma unroll
    for (int o = 0; o < 32; ++o) { const float d = a2[o]-mu; var += d*d; }
    var *= (1.f/32.f);
    rs = 1.f / sqrtf(var + 1e-5f);
    float outv[32];
    #pragma unroll
    for (int o = 0; o < 32; ++o)
        outv[o] = fmaxf((a2[o]-mu)*rs*g2[p*32+o] + be2[p*32+o], 0.f);
    float4* hv = (float4*)&hh[tid*32];
    #pragma unroll
    for (int j = 0; j < 8; ++j)
        hv[j] = make_float4(outv[j*4+0], outv[j*4+1], outv[j*4+2], outv[j*4+3]);
}

// ------------- per-edge messages, pairs 00/01/10 (lane = edge) -------------
// All lanes consume the SAME W3 row -> LDS reads are same-address broadcasts
// (conflict-free). W3 double-buffered through LDS, issue-early/write-late.
// Split from the pair11 kernel so regalloc handles each path separately
// (R7: combined kernel spilled hh4/u -> 20 GB scratch traffic).
__launch_bounds__(128)
__global__ void msg_q012_kernel(const float* __restrict__ hhg,
                                const float* __restrict__ f0g, const float* __restrict__ f1g,
                                const float* __restrict__ w3_00, const float* __restrict__ b3_00,
                                const float* __restrict__ w3_01, const float* __restrict__ b3_01,
                                const float* __restrict__ w3_10, const float* __restrict__ b3_10,
                                const float* __restrict__ bas00g, const float* __restrict__ bas01g,
                                const float* __restrict__ bas10g,
                                const int* __restrict__ esrc, const int* __restrict__ edst,
                                float* __restrict__ acc0, float* __restrict__ acc1,
                                float* __restrict__ deg) {
    __shared__ float4 wq[2][256];     // chunk: 32 rows x 8 float4
    __shared__ float  bbuf[2][32];
    const int tid = threadIdx.x;
    const int q   = blockIdx.x >> 7;          // 0..2 (block-uniform)
    const int grp = blockIdx.x & 127;
    const int e   = (grp << 7) + tid;
    const int s   = esrc[e];
    const int d   = edst[e];

    float4 hh4[8];
    {
        const float4* hv = (const float4*)&hhg[((q << 14) + e) << 5];
        #pragma unroll
        for (int j = 0; j < 8; ++j) hh4[j] = hv[j];
    }

    const float* hw; const float* hb;
    if (q == 0)      { hw = w3_00; hb = b3_00; }
    else if (q == 1) { hw = w3_01; hb = b3_01; }
    else             { hw = w3_10; hb = b3_10; }

    // per-edge u[c] (the factor multiplying R[o][c] for every o)
    float u[32];
    float bm0 = 0.f, bm1 = 0.f, bm2 = 0.f;
    if (q < 2) {
        const float sc = (q == 0) ? bas00g[e] : 1.0f;
        const float4* f0v = (const float4*)&f0g[s << 5];
        #pragma unroll
        for (int j = 0; j < 8; ++j) {
            const float4 v = f0v[j];
            u[j*4+0] = v.x * sc; u[j*4+1] = v.y * sc;
            u[j*4+2] = v.z * sc; u[j*4+3] = v.w * sc;
        }
        if (q == 0) atomicAdd(&deg[d], 1.0f);
        else { bm0 = bas01g[e*3]; bm1 = bas01g[e*3+1]; bm2 = bas01g[e*3+2]; }
    } else {
        const float bn0 = bas10g[e*3], bn1 = bas10g[e*3+1], bn2 = bas10g[e*3+2];
        const float4* f1v = (const float4*)&f1g[s*96];
        #pragma unroll
        for (int gg = 0; gg < 8; ++gg) {
            const float4 v0 = f1v[gg*3+0], v1 = f1v[gg*3+1], v2 = f1v[gg*3+2];
            u[gg*4+0] = bn0*v0.x + bn1*v0.y + bn2*v0.z;
            u[gg*4+1] = bn0*v0.w + bn1*v1.x + bn2*v1.y;
            u[gg*4+2] = bn0*v1.z + bn1*v1.w + bn2*v2.x;
            u[gg*4+3] = bn0*v2.y + bn1*v2.z + bn2*v2.w;
        }
    }

    // prologue: stage chunk 0 (rows 0..31 = o=0)
    {
        const float4* src = (const float4*)&hw[0];
        wq[0][tid]       = src[tid];
        wq[0][tid + 128] = src[tid + 128];
        if (tid < 32) bbuf[0][tid] = hb[tid];
    }
    #pragma unroll 1
    for (int ch = 0; ch < 32; ++ch) {          // chunk ch == output o
        __syncthreads();
        const int cur = ch & 1, nxt = cur ^ 1;
        float4 r0, r1; float rb;
        if (ch < 31) {                          // issue next-chunk loads EARLY
            const float4* src = (const float4*)&hw[(ch + 1) << 10];
            r0 = src[tid];
            r1 = src[tid + 128];
            if (tid < 32) rb = hb[((ch + 1) << 5) + tid];
        }
        float a = 0.f;
        #pragma unroll
        for (int rr = 0; rr < 32; ++rr) {       // row rr == input c
            float a0 = bbuf[cur][rr], a1 = 0.f, a2 = 0.f, a3 = 0.f;
            #pragma unroll
            for (int kq = 0; kq < 8; ++kq) {
                const float4 w = wq[cur][rr*8 + kq];   // broadcast
                a0 = fmaf(w.x, hh4[kq].x, a0);
                a1 = fmaf(w.y, hh4[kq].y, a1);
                a2 = fmaf(w.z, hh4[kq].z, a2);
                a3 = fmaf(w.w, hh4[kq].w, a3);
            }
            a = fmaf((a0 + a1) + (a2 + a3), u[rr], a);
        }
        if (ch < 31) {                          // write-late (vmcnt drained here)
            wq[nxt][tid]       = r0;
            wq[nxt][tid + 128] = r1;
            if (tid < 32) bbuf[nxt][tid] = rb;
        }
        if (q == 1) {
            const int base = ((d << 5) + ch) * 3;
            atomicAdd(&acc1[base+0], a * bm0);
            atomicAdd(&acc1[base+1], a * bm1);
            atomicAdd(&acc1[base+2], a * bm2);
        } else {
            atomicAdd(&acc0[(d << 5) + ch], a);
        }
    }
}

// ------------- per-edge messages, pair 11 o-slices (lane = edge) -----------
// bas11 staged in LDS (stride 27, odd -> 2-way aliasing = free) to keep VGPR
// demand under the cap; everything else mirrors the q012 kernel structure.
__launch_bounds__(128)
__global__ void msg_p11_kernel(const float* __restrict__ hhg,
                               const float* __restrict__ f1g,
                               const float* __restrict__ w3_11, const float* __restrict__ b3_11,
                               const float* __restrict__ bas11g,
                               const int* __restrict__ esrc, const int* __restrict__ edst,
                               float* __restrict__ acc1) {
    __shared__ float4 wq[2][192];     // chunk: 24 rows (8 oo x 3 fi) x 8 float4
    __shared__ float  bbuf[2][24];
    __shared__ float  bas_lds[128*27];
    const int tid = threadIdx.x;
    const int ob  = (blockIdx.x >> 7) << 3;   // o-slice base (block-uniform)
    const int grp = blockIdx.x & 127;
    const int e   = (grp << 7) + tid;
    const int s   = esrc[e];
    const int d   = edst[e];

    float4 hh4[8];
    {
        const float4* hv = (const float4*)&hhg[((3 << 14) + e) << 5];
        #pragma unroll
        for (int j = 0; j < 8; ++j) hh4[j] = hv[j];
    }
    {   // cooperative coalesced stage of bas11 for this block's 128 edges
        const float4* src = (const float4*)(bas11g + grp*3456);
        float4* dst = (float4*)bas_lds;
        #pragma unroll
        for (int j = tid; j < 864; j += 128) dst[j] = src[j];
    }
    float acc[8][3];
    #pragma unroll
    for (int oo = 0; oo < 8; ++oo) { acc[oo][0] = 0.f; acc[oo][1] = 0.f; acc[oo][2] = 0.f; }

    // prologue: stage chunk c=0 (24 rows => 192 float4s; 128 threads -> 2 parts)
    {
        const int seg0 = tid / 24, off0 = tid - seg0*24;                   // 0..127
        wq[0][tid] = ((const float4*)&w3_11[((ob + seg0)*96) << 5])[off0];
        if (tid < 64) {
            const int i1 = tid + 128, seg1 = i1 / 24, off1 = i1 - seg1*24; // 128..191
            wq[0][i1] = ((const float4*)&w3_11[((ob + seg1)*96) << 5])[off1];
        }
        if (tid < 24) bbuf[0][tid] = b3_11[(ob + tid/3)*96 + (tid - (tid/3)*3)];
    }
    const float* bas = &bas_lds[tid*27];
    float s0 = f1g[s*96 + 0], s1v = f1g[s*96 + 1], s2 = f1g[s*96 + 2];
    #pragma unroll 1
    for (int c = 0; c < 32; ++c) {
        __syncthreads();
        const int cur = c & 1, nxt = cur ^ 1;
        float4 r0, r1; float rb;
        float n0, n1, n2;
        if (c < 31) {                            // issue next-chunk loads EARLY
            const int cn = c + 1;
            {
                const int seg = tid / 24, off = tid - seg*24;              // 0..127
                r0 = ((const float4*)&w3_11[(((ob + seg)*96) + cn*3) << 5])[off];
            }
            if (tid < 64) {
                const int i1 = tid + 128;
                const int seg = i1 / 24, off = i1 - seg*24;                // 128..191
                r1 = ((const float4*)&w3_11[(((ob + seg)*96) + cn*3) << 5])[off];
            }
            if (tid < 24) rb = b3_11[(ob + tid/3)*96 + cn*3 + (tid - (tid/3)*3)];
            n0 = f1g[s*96 + cn*3 + 0];
            n1 = f1g[s*96 + cn*3 + 1];
            n2 = f1g[s*96 + cn*3 + 2];
        }
        float t_[3][3];                          // t_[fi][m]
        #pragma unroll
        for (int fi = 0; fi < 3; ++fi)
            #pragma unroll
            for (int m = 0; m < 3; ++m)
                t_[fi][m] = bas[m*9 + fi]*s0 + bas[m*9 + 3 + fi]*s1v + bas[m*9 + 6 + fi]*s2;
        #pragma unroll
        for (int oo = 0; oo < 8; ++oo) {
            #pragma unroll
            for (int fi = 0; fi < 3; ++fi) {
                const int rl = oo*3 + fi;
                float a0 = bbuf[cur][rl], a1 = 0.f, a2 = 0.f, a3 = 0.f;
                #pragma unroll
                for (int kq = 0; kq < 8; ++kq) {
                    const float4 w = wq[cur][rl*8 + kq];   // broadcast
                    a0 = fmaf(w.x, hh4[kq].x, a0);
                    a1 = fmaf(w.y, hh4[kq].y, a1);
                    a2 = fmaf(w.z, hh4[kq].z, a2);
                    a3 = fmaf(w.w, hh4[kq].w, a3);
                }
                const float R = (a0 + a1) + (a2 + a3);
                acc[oo][0] = fmaf(R, t_[fi][0], acc[oo][0]);
                acc[oo][1] = fmaf(R, t_[fi][1], acc[oo][1]);
                acc[oo][2] = fmaf(R, t_[fi][2], acc[oo][2]);
            }
        }
        if (c < 31) {                            // write-late
            wq[nxt][tid] = r0;
            if (tid < 64)  wq[nxt][tid + 128] = r1;
            if (tid < 24)  bbuf[nxt][tid] = rb;
            s0 = n0; s1v = n1; s2 = n2;
        }
    }
    #pragma unroll
    for (int oo = 0; oo < 8; ++oo) {
        const int base = ((d << 5) + ob + oo) * 3;
        atomicAdd(&acc1[base+0], acc[oo][0]);
        atomicAdd(&acc1[base+1], acc[oo][1]);
        atomicAdd(&acc1[base+2], acc[oo][2]);
    }
}

// --------------------------- node epilogue: mean + self + GNormSE3 ---------
__launch_bounds__(256)
__global__ void epi_kernel(const float* __restrict__ acc0, const float* __restrict__ acc1,
                           const float* __restrict__ deg,
                           const float* __restrict__ f0, const float* __restrict__ f1,
                           const float* __restrict__ sw0, const float* __restrict__ sw1,
                           const float* __restrict__ g0v, const float* __restrict__ b0v,
                           const float* __restrict__ nw0, const float* __restrict__ nb0,
                           const float* __restrict__ g1v, const float* __restrict__ b1v,
                           const float* __restrict__ nw1, const float* __restrict__ nb1,
                           float* __restrict__ out) {
    __shared__ float s_sw0[1024], s_sw1[1024], s_nw0[1024], s_nw1[1024];
    __shared__ float s_act0[8][33], s_act1[8][33];
    const int tid = threadIdx.x;
    #pragma unroll
    for (int j = 0; j < 4; ++j) {
        s_sw0[tid + 256*j] = sw0[tid + 256*j];
        s_sw1[tid + 256*j] = sw1[tid + 256*j];
        s_nw0[tid + 256*j] = nw0[tid + 256*j];
        s_nw1[tid + 256*j] = nw1[tid + 256*j];
    }
    const int o = tid & 31, nl = tid >> 5;
    const int n = blockIdx.x * 8 + nl;
    const float dr = deg[n];
    const float dc = fmaxf(dr, 1.0f);
    float v0 = acc0[n*32 + o] / dc;
    float v1[3];
    #pragma unroll
    for (int m = 0; m < 3; ++m) v1[m] = acc1[(n*32 + o)*3 + m] / dc;
    __syncthreads();
    if (dr > 0.f) {   // self-interaction gate: identical to deg/deg_clamped
        #pragma unroll
        for (int c = 0; c < 32; ++c) {
            v0 += s_sw0[o*32 + c] * f0[n*32 + c];
            const float w1c = s_sw1[o*32 + c];
            #pragma unroll
            for (int m = 0; m < 3; ++m) v1[m] += w1c * f1[(n*32 + c)*3 + m];
        }
    }
    const float nrm0 = fmaxf(fabsf(v0), 1e-12f);
    const float nrm1 = fmaxf(sqrtf(v1[0]*v1[0] + v1[1]*v1[1] + v1[2]*v1[2]), 1e-12f);
    float mu0 = nrm0, mu1 = nrm1;
    #pragma unroll
    for (int msk = 16; msk >= 1; msk >>= 1) { mu0 += __shfl_xor(mu0, msk); mu1 += __shfl_xor(mu1, msk); }
    mu0 *= (1.f/32.f); mu1 *= (1.f/32.f);
    const float d0 = nrm0 - mu0, d1 = nrm1 - mu1;
    float s0 = d0*d0, s1 = d1*d1;
    #pragma unroll
    for (int msk = 16; msk >= 1; msk >>= 1) { s0 += __shfl_xor(s0, msk); s1 += __shfl_xor(s1, msk); }
    const float var0 = s0*(1.f/32.f), var1 = s1*(1.f/32.f);
    const float a0 = fmaxf(d0 / sqrtf(var0 + 1e-5f) * g0v[o] + b0v[o], 0.f);
    const float a1 = fmaxf(d1 / sqrtf(var1 + 1e-5f) * g1v[o] + b1v[o], 0.f);
    s_act0[nl][o] = a0; s_act1[nl][o] = a1;
    __syncthreads();
    float t0 = nb0[o], t1 = nb1[o];
    #pragma unroll
    for (int c = 0; c < 32; ++c) {
        t0 += s_act0[nl][c] * s_nw0[o*32 + c];
        t1 += s_act1[nl][c] * s_nw1[o*32 + c];
    }
    float4 ov;
    ov.x = t0 * (v0 / nrm0);
    ov.y = t1 * (v1[0] / nrm1);
    ov.z = t1 * (v1[1] / nrm1);
    ov.w = t1 * (v1[2] / nrm1);
    *(float4*)&out[(n*32 + o)*4] = ov;
}

// ---------------------------------------------------------------------------
extern "C" void kernel_launch(void* const* d_in, const int* in_sizes, int n_in,
                              void* d_out, int out_size, void* d_ws, size_t ws_size,
                              hipStream_t stream) {
    const float* h0    = (const float*)d_in[0];
    const float* h1    = (const float*)d_in[1];
    const float* uph0  = (const float*)d_in[2];
    const float* uph1  = (const float*)d_in[3];
    const float* xyz   = (const float*)d_in[4];
    const float* xyzp  = (const float*)d_in[5];
    const float* r     = (const float*)d_in[6];
    const float* bas00 = (const float*)d_in[7];
    const float* bas01 = (const float*)d_in[8];
    const float* bas10 = (const float*)d_in[9];
    const float* bas11 = (const float*)d_in[10];
    const float* rw1   = (const float*)d_in[11];
    const float* rb1   = (const float*)d_in[12];
    const float* rg1   = (const float*)d_in[13];
    const float* rbe1  = (const float*)d_in[14];
    const float* rw2   = (const float*)d_in[15];
    const float* rb2   = (const float*)d_in[16];
    const float* rg2   = (const float*)d_in[17];
    const float* rbe2  = (const float*)d_in[18];
    const float* w00   = (const float*)d_in[19];
    const float* b00   = (const float*)d_in[20];
    const float* w01   = (const float*)d_in[21];
    const float* b01   = (const float*)d_in[22];
    const float* w10   = (const float*)d_in[23];
    const float* b10   = (const float*)d_in[24];
    const float* w11   = (const float*)d_in[25];
    const float* b11   = (const float*)d_in[26];
    const float* sw0   = (const float*)d_in[27];
    const float* sw1   = (const float*)d_in[28];
    const float* g0    = (const float*)d_in[29];
    const float* bb0   = (const float*)d_in[30];
    const float* nw0   = (const float*)d_in[31];
    const float* nb0   = (const float*)d_in[32];
    const float* g1    = (const float*)d_in[33];
    const float* bb1   = (const float*)d_in[34];
    const float* nw1   = (const float*)d_in[35];
    const float* nb1   = (const float*)d_in[36];
    const int*   esrc  = (const int*)d_in[37];
    const int*   edst  = (const int*)d_in[38];

    float* ws   = (float*)d_ws;
    float* f0   = ws;
    float* f1   = ws + 32768;
    float* hh   = ws + 131072;
    float* acc0 = ws + 2228224;
    float* acc1 = ws + 2260992;
    float* degb = ws + 2359296;
    float* out  = (float*)d_out;

    zero_kernel<<<129, 256, 0, stream>>>(acc0);                    // zeros acc0|acc1|deg
    interp_kernel<<<1024, 128, 0, stream>>>(h0, h1, uph0, uph1, xyz, xyzp, f0, f1);
    trunk_kernel<<<256, 256, 0, stream>>>(r, rw1, rb1, rg1, rbe1, rw2, rb2, rg2, rbe2, hh);
    msg_q012_kernel<<<384, 128, 0, stream>>>(hh, f0, f1, w00, b00, w01, b01, w10, b10,
                                             bas00, bas01, bas10, esrc, edst, acc0, acc1, degb);
    msg_p11_kernel<<<512, 128, 0, stream>>>(hh, f1, w11, b11, bas11, esrc, edst, acc1);
    epi_kernel<<<128, 256, 0, stream>>>(acc0, acc1, degb, f0, f1, sw0, sw1,
                                        g0, bb0, nw0, nb0, g1, bb1, nw1, nb1, out);
}